// Round 4
// baseline (625.392 us; speedup 1.0000x reference)
//
#include <hip/hip_runtime.h>
#include <stdint.h>

typedef float f32x4 __attribute__((ext_vector_type(4)));
typedef __bf16 bf16x8 __attribute__((ext_vector_type(8)));

#define NROWS 65536   // 16 * 4096 x-rows
#define NCODES 4096
#define NDIM 64
#define NSPLIT 8      // stripes per row
#define SCODES 512    // codes per stripe
#define TILES 32      // 512 / 16

// ws layout (bytes):
//   [0x000000, 0x080000): cb = 2*codes bf16   4096*64*2 = 512 KB
//   [0x080000, 0x084000): nc2 = -||c||^2      float[4096]
//   [0x100000, 0x300000): tarr float[NSPLIT][NROWS]  2 MB  (stripe-major!)
//   [0x300000, 0x340000): x2   float[NROWS]          256 KB

// thread per (code, 8 dims): 32768 threads
__global__ __launch_bounds__(256) void prep_codes_k(const float* __restrict__ codes,
                                                    __bf16* __restrict__ cb,
                                                    float* __restrict__ nc2) {
  const int gid = blockIdx.x * 256 + threadIdx.x;
  const int m = gid >> 3;
  const int q = gid & 7;
  const float* src = codes + m * NDIM + q * 8;
  f32x4 v0 = *(const f32x4*)src;
  f32x4 v1 = *(const f32x4*)(src + 4);
  bf16x8 o;
  float s = 0.f;
#pragma unroll
  for (int j = 0; j < 4; j++) {
    o[j]     = (__bf16)(2.0f * v0[j]);   // cb = 2*c (exact bf16 scaling)
    o[j + 4] = (__bf16)(2.0f * v1[j]);
    s += v0[j] * v0[j] + v1[j] * v1[j];
  }
  *(bf16x8*)(cb + m * NDIM + q * 8) = o;
  s += __shfl_xor(s, 1);
  s += __shfl_xor(s, 2);
  s += __shfl_xor(s, 4);
  if (q == 0) nc2[m] = -s;  // tv = 2*x.c - ||c||^2 ; d2 = ||x||^2 - tv
}

// Each wave: 64 x-rows (4 row-tiles) x one 512-code stripe.
// Mapping: rowgrp = blockIdx>>1 (the block PAIR shares x rows; the 4 waves of
// a block share them through L1). stripe = (blockIdx&1)*4 + waveid. Since
// blocks go round-robin to XCDs, each XCD sees 1/4 of x (4 MB, L2-resident)
// and half of cb.
// Operand swap vs R1: codes = A (so C/D row dim = code), x = B.
//   A-frag: lane holds A[m=lane&15][k=quad*8+j]  (same load pattern both ops)
//   C/D 16x16: code = quad*4 + reg, x-row = lane&15.
// => each lane's 4 acc regs are 4 CODES of one x-row: per-tile epilogue is
//    4 adds + 2 max3, no index tracking (indices recovered exactly in
//    nn_final's fp32 rescan, which never triggers for N(0,1) data: min d2~50).
// launch_bounds (256,4): 128-VGPR budget. (256,8) spilled 1.1 GB in R2 —
// do not tighten.
__global__ __launch_bounds__(256, 4) void nn_main(const float* __restrict__ x,
                                                  const __bf16* __restrict__ cb,
                                                  const float* __restrict__ nc2,
                                                  float* __restrict__ tarr,
                                                  float* __restrict__ x2arr) {
  const int lane   = threadIdx.x & 63;
  const int wv     = threadIdx.x >> 6;          // 0..3
  const int rowgrp = blockIdx.x >> 1;           // 0..1023
  const int half   = blockIdx.x & 1;
  const int stripe = half * 4 + wv;             // 0..7
  const int col    = lane & 15;                 // x-row within tile / A m-index
  const int quad   = lane >> 4;

  // ---- x fragments (B operand), loaded once; + ||x||^2 ----
  bf16x8 a[4][2];
  float x2part[4];
#pragma unroll
  for (int rt = 0; rt < 4; rt++) {
    const int row = rowgrp * 64 + rt * 16 + col;
    const float* xr = x + row * NDIM + quad * 8;
    float p = 0.f;
#pragma unroll
    for (int kc = 0; kc < 2; kc++) {
      f32x4 v0 = *(const f32x4*)(xr + kc * 32);
      f32x4 v1 = *(const f32x4*)(xr + kc * 32 + 4);
      bf16x8 af;
#pragma unroll
      for (int j = 0; j < 4; j++) {
        af[j]     = (__bf16)v0[j];
        af[j + 4] = (__bf16)v1[j];
        p += v0[j] * v0[j] + v1[j] * v1[j];
      }
      a[rt][kc] = af;
    }
    x2part[rt] = p;
  }
#pragma unroll
  for (int rt = 0; rt < 4; rt++) {
    float p = x2part[rt];
    p += __shfl_xor(p, 16);
    p += __shfl_xor(p, 32);
    x2part[rt] = p;
  }
  if (half == 0 && wv == 0 && quad == 0) {
#pragma unroll
    for (int rt = 0; rt < 4; rt++) x2arr[rowgrp * 64 + rt * 16 + col] = x2part[rt];
  }

  // ---- main loop: 32 code-tiles of this stripe ----
  float best[4];
#pragma unroll
  for (int rt = 0; rt < 4; rt++) best[rt] = -3.0e38f;

  const int cbase = stripe * SCODES;
  const __bf16* aptr = cb + (cbase + col) * NDIM + quad * 8;  // code A-frags
  const float* nptr = nc2 + cbase + quad * 4;                 // per-lane 4 codes

  bf16x8 c0 = *(const bf16x8*)(aptr);
  bf16x8 c1 = *(const bf16x8*)(aptr + 32);

  for (int t = 0; t < TILES; t++) {
    bf16x8 n0, n1;
    if (t < TILES - 1) {
      n0 = *(const bf16x8*)(aptr + 1024);       // next tile: +16 codes * 64
      n1 = *(const bf16x8*)(aptr + 1024 + 32);
    }
    f32x4 nv = *(const f32x4*)(nptr);           // -||c||^2 for codes quad*4+j
#pragma unroll
    for (int rt = 0; rt < 4; rt++) {
      f32x4 acc = __builtin_amdgcn_mfma_f32_16x16x32_bf16(c0, a[rt][0], (f32x4){0.f, 0.f, 0.f, 0.f}, 0, 0, 0);
      acc = __builtin_amdgcn_mfma_f32_16x16x32_bf16(c1, a[rt][1], acc, 0, 0, 0);
      float t0 = acc[0] + nv[0];
      float t1 = acc[1] + nv[1];
      float t2 = acc[2] + nv[2];
      float t3 = acc[3] + nv[3];
      best[rt] = fmaxf(fmaxf(best[rt], t0), t1);   // -> v_max3_f32
      best[rt] = fmaxf(fmaxf(best[rt], t2), t3);
    }
    c0 = n0;
    c1 = n1;
    aptr += 1024;
    nptr += 16;
  }

  // ---- cross-quad max (4 quads hold disjoint code subsets of same x-row) ----
#pragma unroll
  for (int rt = 0; rt < 4; rt++) {
    float b = best[rt];
    b = fmaxf(b, __shfl_xor(b, 16));
    b = fmaxf(b, __shfl_xor(b, 32));
    if (quad == 0)
      tarr[stripe * NROWS + rowgrp * 64 + rt * 16 + col] = b;  // 64B/line writes
  }
}

// Merge 8 stripes; rows whose bf16 d2min <= 0.5 (never, for this data) get an
// exact fp32 rescan reproducing the reference argmin/within semantics.
__global__ __launch_bounds__(256) void nn_final(const float* __restrict__ tarr,
                                                const float* __restrict__ x2arr,
                                                const float* __restrict__ x,
                                                const float* __restrict__ codes,
                                                int* __restrict__ out) {
  const int row = blockIdx.x * 256 + threadIdx.x;
  float tm = tarr[row];
#pragma unroll
  for (int s = 1; s < NSPLIT; s++) tm = fmaxf(tm, tarr[s * NROWS + row]);
  const float x2 = x2arr[row];
  const float d2b = x2 - tm;  // bf16-path min squared distance
  int res = -1;
  if (d2b <= 0.5f) {  // conservative trigger; exact recompute
    float xv[NDIM];
    const float* xr = x + row * NDIM;
#pragma unroll
    for (int d = 0; d < NDIM; d++) xv[d] = xr[d];
    float bd = 3.0e38f;
    int bi = 0;
    bool within = false;
    for (int m = 0; m < NCODES; m++) {
      const float* c = codes + m * NDIM;
      float dot = 0.f, c2 = 0.f;
#pragma unroll
      for (int d = 0; d < NDIM; d++) {
        dot = fmaf(xv[d], c[d], dot);
        c2 = fmaf(c[d], c[d], c2);
      }
      const float d2 = x2 + c2 - 2.0f * dot;
      if (d2 <= 0.1f) within = true;
      if (d2 < bd) { bd = d2; bi = m; }  // strict < : first-min-wins like argmin
    }
    res = within ? bi : -1;
  }
  out[row] = res;
}

extern "C" void kernel_launch(void* const* d_in, const int* in_sizes, int n_in,
                              void* d_out, int out_size, void* d_ws, size_t ws_size,
                              hipStream_t stream) {
  const float* x = (const float*)d_in[0];      // [65536][64] fp32
  const float* codes = (const float*)d_in[1];  // [4096][64] fp32
  int* out = (int*)d_out;                      // [65536] int32

  char* ws = (char*)d_ws;
  __bf16* cb = (__bf16*)ws;                     // 512 KB
  float* nc2 = (float*)(ws + 0x080000);         // 16 KB
  float* tarr = (float*)(ws + 0x100000);        // 2 MB, [stripe][row]
  float* x2arr = (float*)(ws + 0x300000);       // 256 KB

  prep_codes_k<<<128, 256, 0, stream>>>(codes, cb, nc2);
  nn_main<<<2048, 256, 0, stream>>>(x, cb, nc2, tarr, x2arr);
  nn_final<<<256, 256, 0, stream>>>(tarr, x2arr, x, codes, out);
}

// Round 5
// 381.144 us; speedup vs baseline: 1.6408x; 1.6408x over previous
//
#include <hip/hip_runtime.h>
#include <stdint.h>

typedef float f32x4 __attribute__((ext_vector_type(4)));
typedef __bf16 bf16x8 __attribute__((ext_vector_type(8)));

#define NROWS 65536   // 16 * 4096 x-rows
#define NCODES 4096
#define NDIM 64
#define NSPLIT 8      // stripes per row
#define SCODES 512    // codes per stripe
#define TILES 32      // 512 / 16

// ws layout (bytes):
//   [0x000000, 0x080000): cb = 2*codes bf16   4096*64*2 = 512 KB
//   [0x080000, 0x084000): nc2 = -||c||^2      float[4096]
//   [0x100000, 0x300000): tarr float[NSPLIT][NROWS]  2 MB  (stripe-major)
//   [0x300000, 0x340000): x2   float[NROWS]          256 KB

// thread per (code, 8 dims): 32768 threads
__global__ __launch_bounds__(256) void prep_codes_k(const float* __restrict__ codes,
                                                    __bf16* __restrict__ cb,
                                                    float* __restrict__ nc2) {
  const int gid = blockIdx.x * 256 + threadIdx.x;
  const int m = gid >> 3;
  const int q = gid & 7;
  const float* src = codes + m * NDIM + q * 8;
  f32x4 v0 = *(const f32x4*)src;
  f32x4 v1 = *(const f32x4*)(src + 4);
  bf16x8 o;
  float s = 0.f;
#pragma unroll
  for (int j = 0; j < 4; j++) {
    o[j]     = (__bf16)(2.0f * v0[j]);   // cb = 2*c (exact bf16 scaling)
    o[j + 4] = (__bf16)(2.0f * v1[j]);
    s += v0[j] * v0[j] + v1[j] * v1[j];
  }
  *(bf16x8*)(cb + m * NDIM + q * 8) = o;
  s += __shfl_xor(s, 1);
  s += __shfl_xor(s, 2);
  s += __shfl_xor(s, 4);
  if (q == 0) nc2[m] = -s;  // tv = 2*x.c - ||c||^2 ; d2 = ||x||^2 - tv
}

// Each wave: 64 x-rows (4 row-tiles) x one 512-code stripe.
// Mapping: rowgrp = blockIdx>>1 (block pair shares x rows; 4 waves of a
// block share them through L1). stripe = (blockIdx&1)*4 + waveid.
// Operands: codes = A, x = B.
//   A-frag: lane holds A[m=lane&15][k=quad*8+j]
//   C/D 16x16: code = quad*4 + reg, x-row = lane&15.
// Epilogue fold: C operand of the first MFMA is nv[j] = -||c_{quad*4+j}||^2
// (row-indexed, col-invariant) so acc exits as tv = 2x.c - ||c||^2 directly;
// per-tile epilogue is just 2 v_max3 per row-tile. No index tracking: indices
// recovered by nn_final's exact fp32 rescan (trigger d2b<=4; never fires for
// N(0,1) data, min d2 ~ 40-90).
// CODEGEN NOTES (R2/R4 scars): (256,4) = 128-VGPR budget; (256,8) spilled
// 1.1 GB (R2). NO manual prefetch regs — R4's n0/n1 pair pushed the arch
// partition over and spilled 1 GB scratch (WRITE_SIZE is the tripwire).
__global__ __launch_bounds__(256, 4) void nn_main(const float* __restrict__ x,
                                                  const __bf16* __restrict__ cb,
                                                  const float* __restrict__ nc2,
                                                  float* __restrict__ tarr,
                                                  float* __restrict__ x2arr) {
  const int lane   = threadIdx.x & 63;
  const int wv     = threadIdx.x >> 6;          // 0..3
  const int rowgrp = blockIdx.x >> 1;           // 0..1023
  const int half   = blockIdx.x & 1;
  const int stripe = half * 4 + wv;             // 0..7
  const int col    = lane & 15;                 // x-row within tile
  const int quad   = lane >> 4;

  // ---- x fragments (B operand), loaded once; + ||x||^2 ----
  bf16x8 a[4][2];
  float x2part[4];
#pragma unroll
  for (int rt = 0; rt < 4; rt++) {
    const int row = rowgrp * 64 + rt * 16 + col;
    const float* xr = x + row * NDIM + quad * 8;
    float p = 0.f;
#pragma unroll
    for (int kc = 0; kc < 2; kc++) {
      f32x4 v0 = *(const f32x4*)(xr + kc * 32);
      f32x4 v1 = *(const f32x4*)(xr + kc * 32 + 4);
      bf16x8 af;
#pragma unroll
      for (int j = 0; j < 4; j++) {
        af[j]     = (__bf16)v0[j];
        af[j + 4] = (__bf16)v1[j];
        p += v0[j] * v0[j] + v1[j] * v1[j];
      }
      a[rt][kc] = af;
    }
    x2part[rt] = p;
  }
#pragma unroll
  for (int rt = 0; rt < 4; rt++) {
    float p = x2part[rt];
    p += __shfl_xor(p, 16);
    p += __shfl_xor(p, 32);
    x2part[rt] = p;
  }
  if (half == 0 && wv == 0 && quad == 0) {
#pragma unroll
    for (int rt = 0; rt < 4; rt++) x2arr[rowgrp * 64 + rt * 16 + col] = x2part[rt];
  }

  // ---- main loop: 32 code-tiles of this stripe ----
  float best[4];
#pragma unroll
  for (int rt = 0; rt < 4; rt++) best[rt] = -3.0e38f;

  const int cbase = stripe * SCODES;
  const __bf16* aptr = cb + (cbase + col) * NDIM + quad * 8;  // code A-frags
  const float* nptr = nc2 + cbase + quad * 4;                 // 4 codes/lane

  for (int t = 0; t < TILES; t++) {
    bf16x8 c0 = *(const bf16x8*)(aptr);
    bf16x8 c1 = *(const bf16x8*)(aptr + 32);
    f32x4 nv = *(const f32x4*)(nptr);   // -||c||^2, row-indexed (quad*4+j)
#pragma unroll
    for (int rt = 0; rt < 4; rt++) {
      f32x4 acc = __builtin_amdgcn_mfma_f32_16x16x32_bf16(c0, a[rt][0], nv, 0, 0, 0);
      acc = __builtin_amdgcn_mfma_f32_16x16x32_bf16(c1, a[rt][1], acc, 0, 0, 0);
      best[rt] = fmaxf(fmaxf(best[rt], acc[0]), acc[1]);   // v_max3_f32
      best[rt] = fmaxf(fmaxf(best[rt], acc[2]), acc[3]);
    }
    aptr += 1024;   // +16 codes * 64 dims
    nptr += 16;
  }

  // ---- cross-quad max (quads hold disjoint code subsets of same x-row) ----
#pragma unroll
  for (int rt = 0; rt < 4; rt++) {
    float b = best[rt];
    b = fmaxf(b, __shfl_xor(b, 16));
    b = fmaxf(b, __shfl_xor(b, 32));
    if (quad == 0)
      tarr[stripe * NROWS + rowgrp * 64 + rt * 16 + col] = b;  // 64B lines
  }
}

// Merge 8 stripes; rows whose bf16 d2min <= 4.0 (never, for this data) get an
// exact fp32 rescan reproducing the reference argmin/within semantics.
__global__ __launch_bounds__(256) void nn_final(const float* __restrict__ tarr,
                                                const float* __restrict__ x2arr,
                                                const float* __restrict__ x,
                                                const float* __restrict__ codes,
                                                int* __restrict__ out) {
  const int row = blockIdx.x * 256 + threadIdx.x;
  float tm = tarr[row];
#pragma unroll
  for (int s = 1; s < NSPLIT; s++) tm = fmaxf(tm, tarr[s * NROWS + row]);
  const float x2 = x2arr[row];
  const float d2b = x2 - tm;  // bf16-path min squared distance
  int res = -1;
  if (d2b <= 4.0f) {  // conservative trigger; exact recompute
    const float* xr = x + row * NDIM;
    float bd = 3.0e38f;
    int bi = 0;
    bool within = false;
    for (int m = 0; m < NCODES; m++) {
      const float* c = codes + m * NDIM;
      float dot = 0.f, c2 = 0.f;
#pragma unroll 8
      for (int d = 0; d < NDIM; d++) {
        dot = fmaf(xr[d], c[d], dot);
        c2 = fmaf(c[d], c[d], c2);
      }
      const float d2 = x2 + c2 - 2.0f * dot;
      if (d2 <= 0.1f) within = true;
      if (d2 < bd) { bd = d2; bi = m; }  // strict < : first-min-wins
    }
    res = within ? bi : -1;
  }
  out[row] = res;
}

extern "C" void kernel_launch(void* const* d_in, const int* in_sizes, int n_in,
                              void* d_out, int out_size, void* d_ws, size_t ws_size,
                              hipStream_t stream) {
  const float* x = (const float*)d_in[0];      // [65536][64] fp32
  const float* codes = (const float*)d_in[1];  // [4096][64] fp32
  int* out = (int*)d_out;                      // [65536] int32

  char* ws = (char*)d_ws;
  __bf16* cb = (__bf16*)ws;                     // 512 KB
  float* nc2 = (float*)(ws + 0x080000);         // 16 KB
  float* tarr = (float*)(ws + 0x100000);        // 2 MB, [stripe][row]
  float* x2arr = (float*)(ws + 0x300000);       // 256 KB

  prep_codes_k<<<128, 256, 0, stream>>>(codes, cb, nc2);
  nn_main<<<2048, 256, 0, stream>>>(x, cb, nc2, tarr, x2arr);
  nn_final<<<256, 256, 0, stream>>>(tarr, x2arr, x, codes, out);
}

// Round 6
// 142.478 us; speedup vs baseline: 4.3894x; 2.6751x over previous
//
#include <hip/hip_runtime.h>
#include <stdint.h>

typedef float f32x4 __attribute__((ext_vector_type(4)));
typedef __bf16 bf16x8 __attribute__((ext_vector_type(8)));

#define NROWS 65536   // 16 * 4096 x-rows
#define NCODES 4096
#define NDIM 64
#define NSPLIT 8      // stripes per row
#define SCODES 512    // codes per stripe
#define TILES 32      // 512 / 16

// ws layout (bytes):
//   [0x000000, 0x080000): cb = 2*codes bf16   4096*64*2 = 512 KB
//   [0x080000, 0x084000): nc2 = -||c||^2      float[4096]
//   [0x100000, 0x300000): tarr float[NSPLIT][NROWS]  2 MB  (stripe-major)
//   [0x300000, 0x340000): x2   float[NROWS]          256 KB

// thread per (code, 8 dims): 32768 threads
__global__ __launch_bounds__(256) void prep_codes_k(const float* __restrict__ codes,
                                                    __bf16* __restrict__ cb,
                                                    float* __restrict__ nc2) {
  const int gid = blockIdx.x * 256 + threadIdx.x;
  const int m = gid >> 3;
  const int q = gid & 7;
  const float* src = codes + m * NDIM + q * 8;
  f32x4 v0 = *(const f32x4*)src;
  f32x4 v1 = *(const f32x4*)(src + 4);
  bf16x8 o;
  float s = 0.f;
#pragma unroll
  for (int j = 0; j < 4; j++) {
    o[j]     = (__bf16)(2.0f * v0[j]);   // cb = 2*c (exact bf16 scaling)
    o[j + 4] = (__bf16)(2.0f * v1[j]);
    s += v0[j] * v0[j] + v1[j] * v1[j];
  }
  *(bf16x8*)(cb + m * NDIM + q * 8) = o;
  s += __shfl_xor(s, 1);
  s += __shfl_xor(s, 2);
  s += __shfl_xor(s, 4);
  if (q == 0) nc2[m] = -s;  // tv = 2*x.c - ||c||^2 ; d2 = ||x||^2 - tv
}

// Each wave: 64 x-rows (4 row-tiles) x one 512-code stripe.
// Mapping: rowgrp = blockIdx>>1 (block pair shares x rows; 4 waves of a
// block share them through L1). stripe = (blockIdx&1)*4 + waveid.
// Operands: codes = A, x = B.
//   A-frag: lane holds A[m=lane&15][k=quad*8+j]
//   C/D 16x16: code = quad*4 + reg, x-row = lane&15.
// Epilogue fold: C operand of the first MFMA is nv[j] = -||c_{quad*4+j}||^2
// (row-indexed, col-invariant) so acc exits as tv = 2x.c - ||c||^2 directly;
// per-tile epilogue is 2 v_max3 per row-tile. No index tracking: indices
// recovered by nn_final's exact fp32 rescan (trigger d2b<=4; never fires for
// N(0,1) data, min d2 ~ 40-90).
// CODEGEN SCARS (R2/R4/R5): every launch_bounds min-waves clause made the
// allocator half-split the unified file and SPILL (reported VGPR = exactly
// half the budget: 32@R2, 64@R4/R5, with 0.3-1 GB scratch traffic in
// FETCH/WRITE_SIZE). Plain __launch_bounds__(256) + nounroll on the t-loop
// keeps pressure at the hand-counted ~80 regs. WRITE_SIZE is the tripwire.
__global__ __launch_bounds__(256) void nn_main(const float* __restrict__ x,
                                               const __bf16* __restrict__ cb,
                                               const float* __restrict__ nc2,
                                               float* __restrict__ tarr,
                                               float* __restrict__ x2arr) {
  const int lane   = threadIdx.x & 63;
  const int wv     = threadIdx.x >> 6;          // 0..3
  const int rowgrp = blockIdx.x >> 1;           // 0..1023
  const int half   = blockIdx.x & 1;
  const int stripe = half * 4 + wv;             // 0..7
  const int col    = lane & 15;                 // x-row within tile
  const int quad   = lane >> 4;

  // ---- x fragments (B operand), loaded once; + ||x||^2 ----
  bf16x8 a[4][2];
  float x2part[4];
#pragma unroll
  for (int rt = 0; rt < 4; rt++) {
    const int row = rowgrp * 64 + rt * 16 + col;
    const float* xr = x + row * NDIM + quad * 8;
    float p = 0.f;
#pragma unroll
    for (int kc = 0; kc < 2; kc++) {
      f32x4 v0 = *(const f32x4*)(xr + kc * 32);
      f32x4 v1 = *(const f32x4*)(xr + kc * 32 + 4);
      bf16x8 af;
#pragma unroll
      for (int j = 0; j < 4; j++) {
        af[j]     = (__bf16)v0[j];
        af[j + 4] = (__bf16)v1[j];
        p += v0[j] * v0[j] + v1[j] * v1[j];
      }
      a[rt][kc] = af;
    }
    x2part[rt] = p;
  }
#pragma unroll
  for (int rt = 0; rt < 4; rt++) {
    float p = x2part[rt];
    p += __shfl_xor(p, 16);
    p += __shfl_xor(p, 32);
    x2part[rt] = p;
  }
  if (half == 0 && wv == 0 && quad == 0) {
#pragma unroll
    for (int rt = 0; rt < 4; rt++) x2arr[rowgrp * 64 + rt * 16 + col] = x2part[rt];
  }

  // ---- main loop: 32 code-tiles of this stripe ----
  float best[4];
#pragma unroll
  for (int rt = 0; rt < 4; rt++) best[rt] = -3.0e38f;

  const int cbase = stripe * SCODES;
  const __bf16* aptr = cb + (cbase + col) * NDIM + quad * 8;  // code A-frags
  const float* nptr = nc2 + cbase + quad * 4;                 // 4 codes/lane

#pragma unroll 1
  for (int t = 0; t < TILES; t++) {
    bf16x8 c0 = *(const bf16x8*)(aptr);
    bf16x8 c1 = *(const bf16x8*)(aptr + 32);
    f32x4 nv = *(const f32x4*)(nptr);   // -||c||^2, row-indexed (quad*4+j)
#pragma unroll
    for (int rt = 0; rt < 4; rt++) {
      f32x4 acc = __builtin_amdgcn_mfma_f32_16x16x32_bf16(c0, a[rt][0], nv, 0, 0, 0);
      acc = __builtin_amdgcn_mfma_f32_16x16x32_bf16(c1, a[rt][1], acc, 0, 0, 0);
      best[rt] = fmaxf(fmaxf(best[rt], acc[0]), acc[1]);   // v_max3_f32
      best[rt] = fmaxf(fmaxf(best[rt], acc[2]), acc[3]);
    }
    aptr += 1024;   // +16 codes * 64 dims
    nptr += 16;
  }

  // ---- cross-quad max (quads hold disjoint code subsets of same x-row) ----
#pragma unroll
  for (int rt = 0; rt < 4; rt++) {
    float b = best[rt];
    b = fmaxf(b, __shfl_xor(b, 16));
    b = fmaxf(b, __shfl_xor(b, 32));
    if (quad == 0)
      tarr[stripe * NROWS + rowgrp * 64 + rt * 16 + col] = b;  // 64B lines
  }
}

// Merge 8 stripes; rows whose bf16 d2min <= 4.0 (never, for this data) get an
// exact fp32 rescan reproducing the reference argmin/within semantics.
__global__ __launch_bounds__(256) void nn_final(const float* __restrict__ tarr,
                                                const float* __restrict__ x2arr,
                                                const float* __restrict__ x,
                                                const float* __restrict__ codes,
                                                int* __restrict__ out) {
  const int row = blockIdx.x * 256 + threadIdx.x;
  float tm = tarr[row];
#pragma unroll
  for (int s = 1; s < NSPLIT; s++) tm = fmaxf(tm, tarr[s * NROWS + row]);
  const float x2 = x2arr[row];
  const float d2b = x2 - tm;  // bf16-path min squared distance
  int res = -1;
  if (d2b <= 4.0f) {  // conservative trigger; exact recompute
    const float* xr = x + row * NDIM;
    float bd = 3.0e38f;
    int bi = 0;
    bool within = false;
    for (int m = 0; m < NCODES; m++) {
      const float* c = codes + m * NDIM;
      float dot = 0.f, c2 = 0.f;
#pragma unroll 8
      for (int d = 0; d < NDIM; d++) {
        dot = fmaf(xr[d], c[d], dot);
        c2 = fmaf(c[d], c[d], c2);
      }
      const float d2 = x2 + c2 - 2.0f * dot;
      if (d2 <= 0.1f) within = true;
      if (d2 < bd) { bd = d2; bi = m; }  // strict < : first-min-wins
    }
    res = within ? bi : -1;
  }
  out[row] = res;
}

extern "C" void kernel_launch(void* const* d_in, const int* in_sizes, int n_in,
                              void* d_out, int out_size, void* d_ws, size_t ws_size,
                              hipStream_t stream) {
  const float* x = (const float*)d_in[0];      // [65536][64] fp32
  const float* codes = (const float*)d_in[1];  // [4096][64] fp32
  int* out = (int*)d_out;                      // [65536] int32

  char* ws = (char*)d_ws;
  __bf16* cb = (__bf16*)ws;                     // 512 KB
  float* nc2 = (float*)(ws + 0x080000);         // 16 KB
  float* tarr = (float*)(ws + 0x100000);        // 2 MB, [stripe][row]
  float* x2arr = (float*)(ws + 0x300000);       // 256 KB

  prep_codes_k<<<128, 256, 0, stream>>>(codes, cb, nc2);
  nn_main<<<2048, 256, 0, stream>>>(x, cb, nc2, tarr, x2arr);
  nn_final<<<256, 256, 0, stream>>>(tarr, x2arr, x, codes, out);
}